// Round 6
// baseline (237.964 us; speedup 1.0000x reference)
//
#include <hip/hip_runtime.h>

// XOR-conv as implicit-GEMM MFMA (bf16 inputs, fp32 accum).
// out[b,co,ho,wo] = sum_{ci,kh,kw} x[b,ci,ho+kh,wo+kw] * (1-2*W[co,ci,kh,kw])
// Shapes: B=32, CI=128, H=W=64, CO=256, K=3, HO=WO=62.
//
// R6: (a) phase-correct bank swizzle f(w)=(w^(w>>2))&3 -- every 16-lane b128
// phase covers all 32 banks exactly 2-deep (was 4-deep on half the banks:
// 4.72M conflict cycles = 4/read). (b) LDS cut to exactly 48KB (64-col rows,
// ccol clamped to 63 for masked-lane tail reads) -> 3 blocks/CU under any
// LDS allocation granule. Otherwise identical 2-phase gload_lds pipeline.

typedef __bf16 bf16x8 __attribute__((ext_vector_type(8)));
typedef float  f32x4  __attribute__((ext_vector_type(4)));

#define GLOADLDS16(gp, lp)                                                    \
  __builtin_amdgcn_global_load_lds(                                           \
      (const __attribute__((address_space(1))) unsigned int*)(gp),            \
      (__attribute__((address_space(3))) unsigned int*)(lp), 16, 0, 0)

// ---- merged prepack ----
// blocks [0,8192): x fp32 [b][ci][h][w] -> bf16 xp[b][cc][h][w][q'][8ci],
//   oct slot q' holds ci = cc*32 + q*8 + 0..7 with q = q' ^ f(w),
//   f(w) = (w ^ (w>>2)) & 3   (phase-correct bank swizzle).
// blocks [8192,9344): W fp32 [co][ci][3][3] {0,1} -> effw A-frag order
//   [g=cc*9+e (36)][tile(16)][lane(64)][j(8)]:
//   co = tile*16 + (lane&15), ci = cc*32 + (lane>>4)*8 + j, e = kh*3+kw
__global__ void prepack_kernel(const float* __restrict__ x,
                               const float* __restrict__ Wf,
                               unsigned short* __restrict__ xp,
                               unsigned short* __restrict__ effw) {
  if (blockIdx.x < 8192) {
    int idx = blockIdx.x * 256 + threadIdx.x;   // 32*4*64*64*4 = 2097152 exact
    int qp = idx & 3;
    int w  = (idx >> 2) & 63;
    int h  = (idx >> 8) & 63;
    int cc = (idx >> 14) & 3;
    int b  = idx >> 16;
    int q  = qp ^ ((w ^ (w >> 2)) & 3);
    const float* xb = x + (((size_t)(b * 128 + cc * 32 + q * 8)) * 64 + h) * 64 + w;
    unsigned short o[8];
    #pragma unroll
    for (int k = 0; k < 8; ++k) {
      float f = xb[(size_t)k * 4096];
      __bf16 hh = (__bf16)f;
      unsigned short u; __builtin_memcpy(&u, &hh, 2);
      o[k] = u;
    }
    uint4 v = {(unsigned)o[0] | ((unsigned)o[1] << 16),
               (unsigned)o[2] | ((unsigned)o[3] << 16),
               (unsigned)o[4] | ((unsigned)o[5] << 16),
               (unsigned)o[6] | ((unsigned)o[7] << 16)};
    *(uint4*)(xp + (size_t)idx * 8) = v;
  } else {
    int idx = (blockIdx.x - 8192) * 256 + threadIdx.x;  // 36*16*64*8 = 294912 exact
    int j    = idx & 7;
    int lane = (idx >> 3) & 63;
    int tile = (idx >> 9) & 15;
    int g    = idx >> 13;        // cc*9 + e
    int e    = g % 9;
    int cc   = g / 9;
    int co = tile * 16 + (lane & 15);
    int ci = cc * 32 + (lane >> 4) * 8 + j;
    float w = Wf[(co * 128 + ci) * 9 + e];
    __bf16 h = (__bf16)(1.0f - 2.0f * w);       // exactly +-1
    unsigned short u; __builtin_memcpy(&u, &h, 2);
    effw[idx] = u;
  }
}

// Block: 256 threads = 4 waves. Tile: 64 co x (4 output rows x 64 virtual cols).
// Wave wv owns output row hbase+wv, 4 co 16-tiles, 4 col 16-tiles.
// LDS row: 64 cols x 32 ushorts = 4096B; tail taps (masked lanes) clamp to col 63.
__global__ __launch_bounds__(256, 3)
void xorconv_mfma_kernel(const unsigned short* __restrict__ xp,
                         const unsigned short* __restrict__ effw,
                         float* __restrict__ out) {
  __shared__ __align__(16) unsigned short xs[2][6 * 2048];  // 48.0 KB exact

  const int tid = threadIdx.x;

  // XCD-aware remap: each XCD gets a contiguous work chunk so the 4 co-quarter
  // blocks of one x-window (and adjacent row tiles) share one L2.
  const int lin  = blockIdx.x;                       // 0..2047
  const int work = (lin & 7) * 256 + (lin >> 3);     // bijective (2048 = 8*256)
  const int bxc   = work & 3;          // co quarter
  const int hbt   = (work >> 2) & 15;  // ho tile (4 rows)
  const int bb    = work >> 6;         // batch
  const int co_blk = bxc * 64;
  const int hbase  = hbt * 4;          // 0..60

  const int wv   = tid >> 6;
  const int lane = tid & 63;
  const int quad = lane >> 4;
  const int l16  = lane & 15;

  f32x4 acc[4][4];
  #pragma unroll
  for (int i = 0; i < 4; ++i)
    #pragma unroll
    for (int j = 0; j < 4; ++j)
      acc[i][j] = (f32x4){0.f, 0.f, 0.f, 0.f};

  // ---- af ring (distance-2 prefetch): preload g=0,1 ----
  const unsigned short* wbase = effw + ((size_t)(bxc * 4) * 64 + lane) * 8;
  bf16x8 afb[3][4];
  #pragma unroll
  for (int g = 0; g < 2; ++g)
    #pragma unroll
    for (int mt = 0; mt < 4; ++mt)
      afb[g][mt] = *(const bf16x8*)(wbase + (size_t)g * 8192 + mt * 512);

  const unsigned short* xpb = xp + (size_t)(bb * 4) * 64 * 2048;

  // ---- prologue: stage cc=0 into xs[0] ----
  #pragma unroll
  for (int k = 0; k < 6; ++k) {
    int h_in = hbase + k; if (h_in > 63) h_in = 63;  // clamp: feeds masked rows
    GLOADLDS16(xpb + (size_t)h_in * 2048 + tid * 8,
               &xs[0][k * 2048 + tid * 8]);
  }
  __syncthreads();   // vmcnt(0) drain: buf0 ready

  #pragma unroll
  for (int cc = 0; cc < 4; ++cc) {
    // ---- issue stage(cc+1) into the other buffer; lands during compute ----
    if (cc < 3) {
      const unsigned short* s = xpb + (size_t)((cc + 1) * 64) * 2048;
      #pragma unroll
      for (int k = 0; k < 6; ++k) {
        int h_in = hbase + k; if (h_in > 63) h_in = 63;
        GLOADLDS16(s + (size_t)h_in * 2048 + tid * 8,
                   &xs[(cc + 1) & 1][k * 2048 + tid * 8]);
      }
    }

    // ---- compute cc from current buffer: 9 taps ----
    const unsigned short* xb = xs[cc & 1];
    #pragma unroll
    for (int e = 0; e < 9; ++e) {
      const int g  = cc * 9 + e;
      const int kh = e / 3, kw = e % 3;

      if (g + 2 <= 35) {                       // prefetch af two taps ahead
        const unsigned short* wp = wbase + (size_t)(g + 2) * 8192;
        #pragma unroll
        for (int mt = 0; mt < 4; ++mt)
          afb[(g + 2) % 3][mt] = *(const bf16x8*)(wp + mt * 512);
      }

      const int rr = wv + kh;                  // 0..5
      bf16x8 bfr[4];
      #pragma unroll
      for (int j = 0; j < 4; ++j) {
        int ccol = j * 16 + l16 + kw;          // 0..65
        if (ccol > 63) ccol = 63;              // masked-lane tail: same-addr bcast
        int slot = quad ^ ((ccol ^ (ccol >> 2)) & 3);   // inverse of prepack swz
        bfr[j] = *(const bf16x8*)&xb[rr * 2048 + ccol * 32 + slot * 8];
      }
      #pragma unroll
      for (int mt = 0; mt < 4; ++mt)
        #pragma unroll
        for (int j = 0; j < 4; ++j)
          acc[mt][j] = __builtin_amdgcn_mfma_f32_16x16x32_bf16(
              afb[g % 3][mt], bfr[j], acc[mt][j], 0, 0, 0);
    }
    __syncthreads();   // drains stage(cc+1) DMA; protects buffer swap
  }

  // ---- epilogue: C/D layout col(n)=lane&15, row(m)=quad*4+reg ----
  const int ho = hbase + wv;
  if (ho < 62) {
    #pragma unroll
    for (int mt = 0; mt < 4; ++mt) {
      const int co = co_blk + mt * 16 + quad * 4;
      #pragma unroll
      for (int j = 0; j < 4; ++j) {
        const int wo = j * 16 + l16;
        if (wo < 62) {
          float* op = out + (((size_t)(bb * 256 + co) * 62 + ho) * 62 + wo);
          #pragma unroll
          for (int rg = 0; rg < 4; ++rg)
            op[(size_t)rg * 3844] = acc[mt][j][rg];
        }
      }
    }
  }
}

extern "C" void kernel_launch(void* const* d_in, const int* in_sizes, int n_in,
                              void* d_out, int out_size, void* d_ws, size_t ws_size,
                              hipStream_t stream) {
  const float* x  = (const float*)d_in[0];
  const float* Wf = (const float*)d_in[1];
  float* out = (float*)d_out;
  // workspace: xp (33.55 MB) then effw (0.59 MB)
  unsigned short* xp   = (unsigned short*)d_ws;
  unsigned short* effw = xp + (size_t)16777216;   // 32*4*64*64*4*8

  prepack_kernel<<<dim3(8192 + 1152), dim3(256), 0, stream>>>(x, Wf, xp, effw);

  dim3 grid(2048);   // (co-quarter x ho-tile x batch), XCD-remapped in-kernel
  xorconv_mfma_kernel<<<grid, dim3(256), 0, stream>>>(xp, effw, out);
}